// Round 8
// baseline (287.618 us; speedup 1.0000x reference)
//
#include <hip/hip_runtime.h>
#include <hip/hip_bf16.h>

#define N_NODES 50000
#define N_EDGES 800000
#define N_GRAPHS 64
#define HEADS 4
#define IN_CH 128
#define HID 64
#define F1 256  // HEADS*HID
#define OUT_CH 32
#define F2 128  // HEADS*OUT_CH
#define POOL_SPLITS 16
#define SCAN_B 256
#define SCAN_NB ((N_NODES + SCAN_B - 1) / SCAN_B)  // 196
#define GEMM_GRID (N_NODES / 16)                   // 3125 (16 rows/block, wave=head)
#define COUNT_GRID 782                             // ceil(800000 / (256*4))
#define SCATTER_GRID ((N_EDGES + 255) / 256)       // 3125
#define XPACK_GRID (N_NODES * IN_CH / 8 / 256)     // 3125
#define NP 16                                      // count partitions
#define EPP (N_EDGES / NP)                         // 50000 edges/partition

typedef unsigned short ushortT;
typedef unsigned int uintT;
typedef short v8s __attribute__((ext_vector_type(8)));
typedef float v4f __attribute__((ext_vector_type(4)));
typedef float v2f __attribute__((ext_vector_type(2)));

__device__ __forceinline__ ushortT f2bf(float f) {
    union { float f; unsigned int i; } v; v.f = f;
    unsigned int x = v.i;
    unsigned int r = (x + 0x7fffu + ((x >> 16) & 1u)) >> 16;  // RNE
    return (ushortT)r;
}
__device__ __forceinline__ float bf_lo(uintT w) {
    union { unsigned int i; float f; } v; v.i = w << 16; return v.f;
}
__device__ __forceinline__ float bf_hi(uintT w) {
    union { unsigned int i; float f; } v; v.i = w & 0xffff0000u; return v.f;
}
// fp8 e4m3 (OCP on gfx950) via HW converts
__device__ __forceinline__ unsigned char f2fp8(float f) {
    return (unsigned char)__builtin_amdgcn_cvt_pk_fp8_f32(f, f, 0u, false);
}

// ---- one-time weight pack into bf16 B-fragment image + x fp32->bf16 ----
__device__ __forceinline__ void packW_one(const float* __restrict__ W,
                                          uint4* __restrict__ dst,
                                          int i, int FIN, int FOUT) {
    int KC = FIN / 32;
    int lane = i & 63, g = i >> 6;
    int kc = g % KC, nt = g / KC;
    int n = nt * 16 + (lane & 15);
    int kbase = kc * 32 + (lane >> 4) * 8;
    union { uint4 q; ushortT u[8]; } pk;
#pragma unroll
    for (int j = 0; j < 8; j++) pk.u[j] = f2bf(W[(kbase + j) * FOUT + n]);
    dst[i] = pk.q;
}

__global__ __launch_bounds__(256) void k_pack(
        const float* __restrict__ x, const float* __restrict__ W1,
        const float* __restrict__ W2, uint4* __restrict__ wpk,
        ushortT* __restrict__ xb) {
    int b = blockIdx.x;
    if (b < 32) {
        int i = b * 256 + threadIdx.x;  // 8192 = 4096 (W1) + 4096 (W2)
        if (i < 4096) packW_one(W1, wpk, i, IN_CH, F1);
        else          packW_one(W2, wpk + 4096, i - 4096, F1, F2);
    } else {
        long i = (long)(b - 32) * 256 + threadIdx.x;  // 800000 exactly
        const float4* xf = (const float4*)x + i * 2;
        float4 a = xf[0], c = xf[1];
        union { uint4 q; ushortT u[8]; } pk;
        pk.u[0] = f2bf(a.x); pk.u[1] = f2bf(a.y);
        pk.u[2] = f2bf(a.z); pk.u[3] = f2bf(a.w);
        pk.u[4] = f2bf(c.x); pk.u[5] = f2bf(c.y);
        pk.u[6] = f2bf(c.z); pk.u[7] = f2bf(c.w);
        ((uint4*)xb)[i] = pk.q;
    }
}

// ---- standalone edge count: 4 edges/thread, partitioned counters ----
// (separate dispatch so rocprof attributes count vs GEMM time)
__global__ __launch_bounds__(256) void k_count(
        const int* __restrict__ ei, int* __restrict__ cp,
        int* __restrict__ rank) {
    int e4 = (blockIdx.x * 256 + threadIdx.x) * 4;
    if (e4 < N_EDGES) {  // N_EDGES%4==0 -> all 4 valid together
        int4 dsts = *(const int4*)(ei + N_EDGES + e4);
        int p = e4 / EPP;  // EPP%4==0 -> e4..e4+3 same partition
        int* cpp = cp + p * N_NODES;
        int4 r;
        r.x = atomicAdd(&cpp[dsts.x], 1);
        r.y = atomicAdd(&cpp[dsts.y], 1);
        r.z = atomicAdd(&cpp[dsts.z], 1);
        r.w = atomicAdd(&cpp[dsts.w], 1);
        *(int4*)(rank + e4) = r;
    }
}

// ---- MFMA GEMM, column-split: block = 16 rows, wave w = head w ----
// Batched load issue with a sched_barrier(0) fence: round-6 attempt had the
// compiler SINK the W loads back into the MFMA loop (VGPR 44 proved it).
// The fence pins all af/bu loads before the MFMA burst -> one latency burst
// per wave instead of 16 serialized L2 round-trips.
template <int FIN, int FOUT>
__device__ __forceinline__ void gemm_body(const ushortT* __restrict__ A,
                                          const uint4* __restrict__ Wpk,
                                          const float* __restrict__ ASrc,
                                          const float* __restrict__ ADst,
                                          unsigned char* __restrict__ out,
                                          float* __restrict__ s_out_g,
                                          float* __restrict__ d_out_g,
                                          int bid) {
    constexpr int KC = FIN / 32;
    constexpr int NTH = (FOUT / HEADS) / 16;  // nt tiles per head (4 or 2)
    int tid = threadIdx.x;
    int wave = tid >> 6, lane = tid & 63;     // wave == head
    long row0 = (long)bid * 16;
    int m = lane & 15, b = lane >> 4;

    // ---- batched load issue (no MFMA between loads) ----
    union { v8s v; uint4 q; } af[KC];
    union { v8s v; uint4 q; } bu[NTH][KC];
#pragma unroll
    for (int kc = 0; kc < KC; kc++)
        af[kc].q = *(const uint4*)(A + (row0 + m) * FIN + kc * 32 + b * 8);
#pragma unroll
    for (int j = 0; j < NTH; j++)
#pragma unroll
        for (int kc = 0; kc < KC; kc++)
            bu[j][kc].q = Wpk[((wave * NTH + j) * KC + kc) * 64 + lane];

    // fence: nothing crosses -> loads stay batched ahead of the MFMA burst
    __builtin_amdgcn_sched_barrier(0);

    // ---- MFMA burst ----
    v4f c[NTH];
#pragma unroll
    for (int j = 0; j < NTH; j++) {
        c[j] = (v4f){0.f, 0.f, 0.f, 0.f};
#pragma unroll
        for (int kc = 0; kc < KC; kc++)
            c[j] = __builtin_amdgcn_mfma_f32_16x16x32_bf16(af[kc].v, bu[j][kc].v,
                                                           c[j], 0, 0, 0);
    }

    // ---- epilogue: fp8 store + fused s/d attention terms ----
    float sp[4] = {0,0,0,0}, dp[4] = {0,0,0,0};
#pragma unroll
    for (int j = 0; j < NTH; j++) {
        // C/D: col = lane&15, row = (lane>>4)*4 + reg   [measured m89/m91]
        int col = (wave * NTH + j) * 16 + m;
        float av = ASrc[col], dv = ADst[col];
#pragma unroll
        for (int reg = 0; reg < 4; reg++) {
            out[(row0 + b * 4 + reg) * FOUT + col] = f2fp8(c[j][reg]);
            sp[reg] += c[j][reg] * av;
            dp[reg] += c[j][reg] * dv;
        }
    }
    // reduce over the 16 m-lanes (within each b-group) -> head total
#pragma unroll
    for (int o = 1; o < 16; o <<= 1) {
#pragma unroll
        for (int reg = 0; reg < 4; reg++) {
            sp[reg] += __shfl_xor(sp[reg], o, 64);
            dp[reg] += __shfl_xor(dp[reg], o, 64);
        }
    }
    if (m == 0) {
#pragma unroll
        for (int reg = 0; reg < 4; reg++) {
            s_out_g[(row0 + b * 4 + reg) * HEADS + wave] = sp[reg];
            d_out_g[(row0 + b * 4 + reg) * HEADS + wave] = dp[reg];
        }
    }
}

// needs ~116 VGPR live (af 16 + bu 64 + c 16 + addr) -> cap 128 (4 waves/EU)
__global__ __launch_bounds__(256, 4) void k_gemm1(
        const ushortT* __restrict__ xb, const uint4* __restrict__ wpk,
        const float* __restrict__ asrc1, const float* __restrict__ adst1,
        unsigned char* __restrict__ u_h, float* __restrict__ f_s,
        float* __restrict__ f_d) {
    gemm_body<IN_CH, F1>(xb, wpk, asrc1, adst1, u_h, f_s, f_d, blockIdx.x);
}

// needs ~136 VGPR live (af 32 + bu 64 + c 8 + addr) -> cap 170 (3 waves/EU)
__global__ __launch_bounds__(256, 3) void k_gemm2(
        const ushortT* __restrict__ A, const uint4* __restrict__ wpk2,
        const float* __restrict__ asrc2, const float* __restrict__ adst2,
        unsigned char* __restrict__ u_h, float* __restrict__ f_s,
        float* __restrict__ f_d) {
    gemm_body<F1, F2>(A, wpk2, asrc2, adst2, u_h, f_s, f_d, blockIdx.x);
}

// ---- scan1: fold the NP partition counts per node (in-place exclusive
// prefix over p, so scatter can add cp[p][dst]) + block-level scan ----
__global__ void k_scan1(int* __restrict__ cp, int* __restrict__ offs,
                        int* __restrict__ bsum) {
    __shared__ int sh[SCAN_B];
    int b = blockIdx.x, t = threadIdx.x;
    int i = b * SCAN_B + t;
    int v = 0;
    if (i < N_NODES) {
        int run = 0;
#pragma unroll
        for (int p = 0; p < NP; p++) {
            int c = cp[p * N_NODES + i];
            cp[p * N_NODES + i] = run;  // exclusive prefix over partitions
            run += c;
        }
        v = run;
    }
    sh[t] = v;
    __syncthreads();
    for (int o = 1; o < SCAN_B; o <<= 1) {
        int add = (t >= o) ? sh[t - o] : 0;
        __syncthreads();
        sh[t] += add;
        __syncthreads();
    }
    if (i < N_NODES) offs[i] = sh[t] - v;  // block-local exclusive
    if (t == SCAN_B - 1) bsum[b] = sh[t];
}

__global__ void k_scan2(const int* __restrict__ bsum, int* __restrict__ bbase,
                        int* __restrict__ offs, const int* __restrict__ batch,
                        int* __restrict__ bounds) {
    __shared__ int sh[SCAN_B];
    int t = threadIdx.x;
    int v = (t < SCAN_NB) ? bsum[t] : 0;
    sh[t] = v;
    __syncthreads();
    for (int o = 1; o < SCAN_B; o <<= 1) {
        int add = (t >= o) ? sh[t - o] : 0;
        __syncthreads();
        sh[t] += add;
        __syncthreads();
    }
    if (t < SCAN_NB) bbase[t] = sh[t] - v;      // exclusive base per block
    if (t == SCAN_B - 1) offs[N_NODES] = sh[t]; // grand total (= N_EDGES)
    // fused: graph boundaries via binary search on sorted batch
    if (t <= N_GRAPHS) {
        int lo = 0, hi = N_NODES;
        while (lo < hi) {
            int mid = (lo + hi) >> 1;
            if (batch[mid] < t) lo = mid + 1; else hi = mid;
        }
        bounds[t] = lo;
    }
}

// ---- scatter: ATOMIC-FREE (partition prefix + in-partition rank) ----
__global__ void k_scatter(const int* __restrict__ ei, const int* __restrict__ offs,
                          const int* __restrict__ bbase, const int* __restrict__ rank,
                          const int* __restrict__ cp, int* __restrict__ csr_src) {
    int e = blockIdx.x * blockDim.x + threadIdx.x;
    if (e >= N_EDGES) return;
    int src = ei[e], dst = ei[N_EDGES + e];
    int p = e / EPP;
    int pos = offs[dst] + bbase[dst >> 8] + cp[p * N_NODES + dst] + rank[e];
    csr_src[pos] = src;
}

// ---- fused segment-softmax + aggregation: TWO nodes per wave (32 lanes
// each), no barriers. Mean degree 16: 2 nodes/wave halves wave-instructions
// per edge (measured bottleneck: VALU issue). ----
template <int C, int VEC, int WPB, int CHUNK>
__global__ __launch_bounds__(64 * WPB) void k_agg(
        const unsigned char* __restrict__ hb, const float* __restrict__ s,
        const float* __restrict__ d, const int* __restrict__ offs,
        const int* __restrict__ bbase, const int* __restrict__ csr_src,
        const float* __restrict__ bias, ushortT* __restrict__ xout) {
    constexpr int F = HEADS * C;
    constexpr int TPN = F / VEC;  // lanes per node
    static_assert(TPN == 32, "two nodes per wave");
    static_assert(C / VEC == 8, "head = tl>>3");
    static_assert(N_NODES % (WPB * 2) == 0, "exact grid");
    __shared__ int lsrc[WPB][2][CHUNK];
    __shared__ float lex[WPB][2][CHUNK * HEADS];
    int wv = threadIdx.x >> 6;
    int t = threadIdx.x & 63;
    int half = t >> 5, tl = t & 31;
    int n = (blockIdx.x * WPB + wv) * 2 + half;
    int h = tl >> 3;
    int beg = offs[n] + bbase[n >> 8];
    int np1 = n + 1;
    int end = (np1 < N_NODES) ? offs[np1] + bbase[np1 >> 8] : offs[N_NODES];
    float4 dn = *(const float4*)(d + n * 4);

    // implicit self-loop: init sumex/acc from own s,d,h (outside the hot loop)
    float4 svn = *(const float4*)(s + n * 4);
    float ssel = (h == 0) ? svn.x : (h == 1) ? svn.y : (h == 2) ? svn.z : svn.w;
    float dsel = (h == 0) ? dn.x : (h == 1) ? dn.y : (h == 2) ? dn.z : dn.w;
    float es = ssel + dsel; es = es > 0.f ? es : 0.2f * es;
    float exs = __expf(es);
    float sumex = exs;
    float acc[VEC];
    if (VEC == 8) {
        uint2 w = ((const uint2*)hb)[(long)n * TPN + tl];
        v2f p0 = __builtin_amdgcn_cvt_pk_f32_fp8(w.x, false);
        v2f p1 = __builtin_amdgcn_cvt_pk_f32_fp8(w.x, true);
        v2f p2 = __builtin_amdgcn_cvt_pk_f32_fp8(w.y, false);
        v2f p3 = __builtin_amdgcn_cvt_pk_f32_fp8(w.y, true);
        acc[0] = exs * p0.x; acc[1] = exs * p0.y;
        acc[2] = exs * p1.x; acc[3] = exs * p1.y;
        acc[4] = exs * p2.x; acc[5] = exs * p2.y;
        acc[6] = exs * p3.x; acc[7] = exs * p3.y;
    } else {
        uintT w = ((const uintT*)hb)[(long)n * TPN + tl];
        v2f p0 = __builtin_amdgcn_cvt_pk_f32_fp8(w, false);
        v2f p1 = __builtin_amdgcn_cvt_pk_f32_fp8(w, true);
        acc[0] = exs * p0.x; acc[1] = exs * p0.y;
        acc[2] = exs * p1.x; acc[3] = exs * p1.y;
    }

    int tot = end - beg;                      // uniform within a half
    int totO = __shfl_xor(tot, 32, 64);       // other half's count
    int maxTot = max(tot, totO);
    for (int base = 0; base < maxTot; base += CHUNK) {
        int cnt = min(CHUNK, tot - base); if (cnt < 0) cnt = 0;
        int cntW = min(CHUNK, maxTot - base);  // wave-uniform loop bound
        // phase 1: each half stages its own node's edges (32 lanes active)
        for (int i = tl; i < cnt; i += TPN) {
            int sn = csr_src[beg + base + i];
            lsrc[wv][half][i] = sn;
            float4 sv = *(const float4*)(s + sn * 4);
            float e0 = sv.x + dn.x; e0 = e0 > 0.f ? e0 : 0.2f * e0;
            float e1 = sv.y + dn.y; e1 = e1 > 0.f ? e1 : 0.2f * e1;
            float e2 = sv.z + dn.z; e2 = e2 > 0.f ? e2 : 0.2f * e2;
            float e3 = sv.w + dn.w; e3 = e3 > 0.f ? e3 : 0.2f * e3;
            float4 exv = { __expf(e0), __expf(e1), __expf(e2), __expf(e3) };
            *(float4*)&lex[wv][half][i * 4] = exv;
        }
        // intra-wave LDS write->read ordering (no block barrier needed)
        asm volatile("s_waitcnt lgkmcnt(0)" ::: "memory");
        // phase 2: both halves accumulate in lockstep; shorter half padded
        // with ex=0 / sn=0 (branchless, finite data -> adds exact 0)
#pragma unroll 4
        for (int i = 0; i < cntW; i++) {
            bool act = i < cnt;
            float ex = act ? lex[wv][half][i * 4 + h] : 0.f;
            int sn = act ? lsrc[wv][half][i] : 0;
            sumex += ex;
            if (VEC == 8) {
                uint2 w = ((const uint2*)hb)[(long)sn * TPN + tl];
                v2f p0 = __builtin_amdgcn_cvt_pk_f32_fp8(w.x, false);
                v2f p1 = __builtin_amdgcn_cvt_pk_f32_fp8(w.x, true);
                v2f p2 = __builtin_amdgcn_cvt_pk_f32_fp8(w.y, false);
                v2f p3 = __builtin_amdgcn_cvt_pk_f32_fp8(w.y, true);
                acc[0] += ex * p0.x; acc[1] += ex * p0.y;
                acc[2] += ex * p1.x; acc[3] += ex * p1.y;
                acc[4] += ex * p2.x; acc[5] += ex * p2.y;
                acc[6] += ex * p3.x; acc[7] += ex * p3.y;
            } else {
                uintT w = ((const uintT*)hb)[(long)sn * TPN + tl];
                v2f p0 = __builtin_amdgcn_cvt_pk_f32_fp8(w, false);
                v2f p1 = __builtin_amdgcn_cvt_pk_f32_fp8(w, true);
                acc[0] += ex * p0.x; acc[1] += ex * p0.y;
                acc[2] += ex * p1.x; acc[3] += ex * p1.y;
            }
        }
        asm volatile("" ::: "memory");
    }
    float inv = 1.f / (sumex + 1e-16f);
    float o[VEC];
#pragma unroll
    for (int j = 0; j < VEC; j++)
        o[j] = fmaxf(acc[j] * inv + bias[tl * VEC + j], 0.f);
    if (VEC == 8) {
        uint4 pk;
        pk.x = (uintT)f2bf(o[0]) | ((uintT)f2bf(o[1]) << 16);
        pk.y = (uintT)f2bf(o[2]) | ((uintT)f2bf(o[3]) << 16);
        pk.z = (uintT)f2bf(o[4]) | ((uintT)f2bf(o[5]) << 16);
        pk.w = (uintT)f2bf(o[6]) | ((uintT)f2bf(o[7]) << 16);
        ((uint4*)xout)[(long)n * TPN + tl] = pk;
    } else {
        uint2 pk;
        pk.x = (uintT)f2bf(o[0]) | ((uintT)f2bf(o[1]) << 16);
        pk.y = (uintT)f2bf(o[2]) | ((uintT)f2bf(o[3]) << 16);
        ((uint2*)xout)[(long)n * TPN + tl] = pk;
    }
}

// ---- pool partials over bf16 x2: block (g,s) sums a contiguous slice ----
__global__ void k_pool_partial(const ushortT* __restrict__ x2, const int* __restrict__ bounds,
                               float* __restrict__ partial) {
    int g = blockIdx.x, s = blockIdx.y;
    int t = threadIdx.x;  // F2 threads
    int n0 = bounds[g], n1 = bounds[g + 1];
    int len = n1 - n0;
    int a = n0 + (int)((long)len * s / POOL_SPLITS);
    int b = n0 + (int)((long)len * (s + 1) / POOL_SPLITS);
    float acc = 0.f;
    for (int n = a; n < b; n++) acc += bf_lo((uintT)x2[(long)n * F2 + t]);
    partial[((long)g * POOL_SPLITS + s) * F2 + t] = acc;
}

// ---- head: block per graph — reduce partials, mean, logits, softmax ----
__global__ void k_head(const float* __restrict__ partial, const int* __restrict__ bounds,
                       const float* __restrict__ Wout, const float* __restrict__ bout,
                       float* __restrict__ out) {
    __shared__ float red0[F2], red1[F2];
    int g = blockIdx.x;
    int t = threadIdx.x;
    int cntN = bounds[g + 1] - bounds[g];
    float cnt = fmaxf((float)cntN, 1.0f);
    float sum = 0.f;
    for (int s = 0; s < POOL_SPLITS; s++)
        sum += partial[((long)g * POOL_SPLITS + s) * F2 + t];
    float p = sum / cnt;
    red0[t] = p * Wout[t * 2 + 0];
    red1[t] = p * Wout[t * 2 + 1];
    __syncthreads();
    for (int off = F2 / 2; off > 0; off >>= 1) {
        if (t < off) { red0[t] += red0[t + off]; red1[t] += red1[t + off]; }
        __syncthreads();
    }
    if (t == 0) {
        float l0 = red0[0] + bout[0];
        float l1 = red1[0] + bout[1];
        float m = fmaxf(l0, l1);
        float e0 = __expf(l0 - m), e1 = __expf(l1 - m);
        float inv = 1.f / (e0 + e1);
        out[g * 2 + 0] = e0 * inv;
        out[g * 2 + 1] = e1 * inv;
    }
}

extern "C" void kernel_launch(void* const* d_in, const int* in_sizes, int n_in,
                              void* d_out, int out_size, void* d_ws, size_t ws_size,
                              hipStream_t stream) {
    const float* x     = (const float*)d_in[0];
    const int*   ei    = (const int*)d_in[1];
    const int*   batch = (const int*)d_in[2];
    const float* W1    = (const float*)d_in[3];
    const float* asrc1 = (const float*)d_in[4];
    const float* adst1 = (const float*)d_in[5];
    const float* b1    = (const float*)d_in[6];
    const float* W2    = (const float*)d_in[7];
    const float* asrc2 = (const float*)d_in[8];
    const float* adst2 = (const float*)d_in[9];
    const float* b2    = (const float*)d_in[10];
    const float* Wout  = (const float*)d_in[11];
    const float* bout  = (const float*)d_in[12];

    char* ws = (char*)d_ws;
    size_t off = 0;
    auto alloc = [&](size_t bytes) -> void* {
        void* p = ws + off;
        off += (bytes + 255) / 256 * 256;
        return p;
    };
    unsigned char* u_h = (unsigned char*)alloc((size_t)N_NODES * F1);  // fp8 h (both layers)
    ushortT* u_x1  = (ushortT*)alloc(sizeof(ushortT) * (size_t)N_NODES * F1);
    ushortT* u_x2  = (ushortT*)alloc(sizeof(ushortT) * (size_t)N_NODES * F2);
    ushortT* xb    = (ushortT*)alloc(sizeof(ushortT) * (size_t)N_NODES * IN_CH);
    uint4*   wpk   = (uint4*)alloc(sizeof(uint4) * 8192);  // W1|W2 fragment images
    float*   f_s   = (float*)alloc(sizeof(float) * (size_t)N_NODES * HEADS);
    float*   f_d   = (float*)alloc(sizeof(float) * (size_t)N_NODES * HEADS);
    int*     i_cp  = (int*)alloc(sizeof(int) * (size_t)NP * N_NODES);  // partitioned counters
    int*     i_off = (int*)alloc(sizeof(int) * (size_t)(N_NODES + 1));
    int*     i_rnk = (int*)alloc(sizeof(int) * (size_t)N_EDGES);
    int*     i_csr = (int*)alloc(sizeof(int) * (size_t)N_EDGES);
    int*     i_bnd = (int*)alloc(sizeof(int) * (size_t)(N_GRAPHS + 1));
    int*     i_bs  = (int*)alloc(sizeof(int) * SCAN_NB);
    int*     i_bb  = (int*)alloc(sizeof(int) * SCAN_NB);
    float*   f_prt = (float*)alloc(sizeof(float) * (size_t)N_GRAPHS * POOL_SPLITS * F2);
    (void)ws_size; (void)in_sizes; (void)n_in; (void)out_size;

    hipMemsetAsync(i_cp, 0, sizeof(int) * (size_t)NP * N_NODES, stream);

    // count standalone (attribution: separate rocprof dispatch)
    k_count<<<COUNT_GRID, 256, 0, stream>>>(ei, i_cp, i_rnk);

    // one-time packs: W1/W2 -> bf16 fragment image, x -> bf16 rows
    k_pack<<<32 + XPACK_GRID, 256, 0, stream>>>(x, W1, W2, wpk, xb);

    // gemm1 standalone (forced batched-load preload)
    k_gemm1<<<GEMM_GRID, 256, 0, stream>>>(xb, wpk, asrc1, adst1, u_h, f_s, f_d);

    // scans (+partition fold, +bounds); atomic-free scatter
    k_scan1<<<SCAN_NB, SCAN_B, 0, stream>>>(i_cp, i_off, i_bs);
    k_scan2<<<1, SCAN_B, 0, stream>>>(i_bs, i_bb, i_off, batch, i_bnd);
    k_scatter<<<SCATTER_GRID, 256, 0, stream>>>(ei, i_off, i_bb, i_rnk, i_cp, i_csr);

    int agg_grid = N_NODES / (4 * 2);  // 2 nodes/wave, 4 waves/block = 6250

    // Layer 1 aggregation (fp8 gather, 2 nodes per wave, VEC=8)
    k_agg<HID, 8, 4, 128><<<agg_grid, 256, 0, stream>>>(
        u_h, f_s, f_d, i_off, i_bb, i_csr, b1, u_x1);

    // Layer 2
    k_gemm2<<<GEMM_GRID, 256, 0, stream>>>(u_x1, wpk + 4096, asrc2, adst2,
                                           u_h, f_s, f_d);
    k_agg<OUT_CH, 4, 4, 128><<<agg_grid, 256, 0, stream>>>(
        u_h, f_s, f_d, i_off, i_bb, i_csr, b2, u_x2);

    // Pool (1024 blocks, machine-filling) + tiny head
    dim3 pgrid(N_GRAPHS, POOL_SPLITS);
    k_pool_partial<<<pgrid, F2, 0, stream>>>(u_x2, i_bnd, f_prt);
    k_head<<<N_GRAPHS, F2, 0, stream>>>(f_prt, i_bnd, Wout, bout, (float*)d_out);
}

// Round 9
// 265.873 us; speedup vs baseline: 1.0818x; 1.0818x over previous
//
#include <hip/hip_runtime.h>
#include <hip/hip_bf16.h>

#define N_NODES 50000
#define N_EDGES 800000
#define N_GRAPHS 64
#define HEADS 4
#define IN_CH 128
#define HID 64
#define F1 256  // HEADS*HID
#define OUT_CH 32
#define F2 128  // HEADS*OUT_CH
#define POOL_SPLITS 16
#define SCAN_B 256
#define SCAN_NB ((N_NODES + SCAN_B - 1) / SCAN_B)  // 196
#define GEMM_GRID ((N_NODES + 127) / 128)          // 391 (32 rows/wave)
#define COUNT_GRID ((N_EDGES + 255) / 256)         // 3125

typedef unsigned short ushortT;
typedef unsigned int uintT;
typedef short v8s __attribute__((ext_vector_type(8)));
typedef float v4f __attribute__((ext_vector_type(4)));
typedef float v2f __attribute__((ext_vector_type(2)));

__device__ __forceinline__ ushortT f2bf(float f) {
    union { float f; unsigned int i; } v; v.f = f;
    unsigned int x = v.i;
    unsigned int r = (x + 0x7fffu + ((x >> 16) & 1u)) >> 16;  // RNE
    return (ushortT)r;
}
__device__ __forceinline__ float bf_lo(uintT w) {
    union { unsigned int i; float f; } v; v.i = w << 16; return v.f;
}
__device__ __forceinline__ float bf_hi(uintT w) {
    union { unsigned int i; float f; } v; v.i = w & 0xffff0000u; return v.f;
}
// fp8 e4m3 (OCP on gfx950) via HW converts
__device__ __forceinline__ unsigned char f2fp8(float f) {
    return (unsigned char)__builtin_amdgcn_cvt_pk_fp8_f32(f, f, 0u, false);
}

// ---- one-time weight pack into bf16 B-fragment image (W only: x is
// consumed fp32 directly by gemm1 -> the 3125-block x-pack kernel and its
// serial launch are deleted; single stream means launches serialize, so
// fewer+fatter kernels win) ----
__device__ __forceinline__ void packW_one(const float* __restrict__ W,
                                          uint4* __restrict__ dst,
                                          int i, int FIN, int FOUT) {
    int KC = FIN / 32;
    int lane = i & 63, g = i >> 6;
    int kc = g % KC, nt = g / KC;
    int n = nt * 16 + (lane & 15);
    int kbase = kc * 32 + (lane >> 4) * 8;
    union { uint4 q; ushortT u[8]; } pk;
#pragma unroll
    for (int j = 0; j < 8; j++) pk.u[j] = f2bf(W[(kbase + j) * FOUT + n]);
    dst[i] = pk.q;
}

__global__ __launch_bounds__(256) void k_packw(
        const float* __restrict__ W1, const float* __restrict__ W2,
        uint4* __restrict__ wpk) {
    int i = blockIdx.x * 256 + threadIdx.x;  // 8192 = 4096 (W1) + 4096 (W2)
    if (i < 4096) packW_one(W1, wpk, i, IN_CH, F1);
    else          packW_one(W2, wpk + 4096, i - 4096, F1, F2);
}

// ---- MFMA GEMM body + fused s,d epilogue; 2 row-tiles (32 rows) per wave ----
// NO LDS: W (64 KB, shared by all blocks) is L2-resident; B fragments read
// straight from the prepacked image via coalesced dwordx4. ABF16=false reads
// fp32 A with inline f2bf (gemm1); true reads bf16 A (gemm2).
template <int FIN, int FOUT, bool ABF16>
__device__ __forceinline__ void gemm_body(const void* __restrict__ A,
                                          const uint4* __restrict__ Wpk,
                                          const float* __restrict__ ASrc,
                                          const float* __restrict__ ADst,
                                          unsigned char* __restrict__ out,
                                          float* __restrict__ s_out_g,
                                          float* __restrict__ d_out_g,
                                          int nrows, int bid) {
    constexpr int KC = FIN / 32;
    constexpr int NT = FOUT / 16;
    constexpr int NTH = (FOUT / HEADS) / 16;  // nt tiles per head
    int tid = threadIdx.x;
    int wave = tid >> 6, lane = tid & 63;
    long rowA = (long)bid * 128 + wave * 32;
    long rowB = rowA + 16;
    bool doA = rowA < nrows, doB = rowB < nrows;  // wave-uniform (nrows%16==0)
    if (!doA) return;
    int m = lane & 15, b = lane >> 4;

    v8s afA[KC], afB[KC];
    if (ABF16) {
        const ushortT* Ab = (const ushortT*)A;
#pragma unroll
        for (int kc = 0; kc < KC; kc++) {
            union { v8s v; uint4 q; } u;
            u.q = *(const uint4*)(Ab + (rowA + m) * FIN + kc * 32 + b * 8);
            afA[kc] = u.v;
            if (doB) {
                u.q = *(const uint4*)(Ab + (rowB + m) * FIN + kc * 32 + b * 8);
                afB[kc] = u.v;
            }
        }
    } else {
        const float* Af = (const float*)A;
#pragma unroll
        for (int kc = 0; kc < KC; kc++) {
            union { v8s v; ushortT u[8]; } u;
            const float* p = Af + (rowA + m) * FIN + kc * 32 + b * 8;
#pragma unroll
            for (int j = 0; j < 8; j++) u.u[j] = f2bf(p[j]);
            afA[kc] = u.v;
            if (doB) {
                const float* q = Af + (rowB + m) * FIN + kc * 32 + b * 8;
#pragma unroll
                for (int j = 0; j < 8; j++) u.u[j] = f2bf(q[j]);
                afB[kc] = u.v;
            }
        }
    }

    float spA[4] = {0,0,0,0}, dpA[4] = {0,0,0,0};
    float spB[4] = {0,0,0,0}, dpB[4] = {0,0,0,0};
    float skA[4], dkA[4], skB[4], dkB[4];
#pragma unroll
    for (int nt = 0; nt < NT; nt++) {
        v4f cA = {0.f, 0.f, 0.f, 0.f}, cB = {0.f, 0.f, 0.f, 0.f};
#pragma unroll
        for (int kc = 0; kc < KC; kc++) {
            union { v8s v; uint4 q; } bu;
            bu.q = Wpk[(nt * KC + kc) * 64 + lane];
            cA = __builtin_amdgcn_mfma_f32_16x16x32_bf16(afA[kc], bu.v, cA, 0, 0, 0);
            if (doB)
                cB = __builtin_amdgcn_mfma_f32_16x16x32_bf16(afB[kc], bu.v, cB, 0, 0, 0);
        }
        // C/D: col = lane&15, row = (lane>>4)*4 + reg   [measured m89/m91]
        int col = nt * 16 + m;
        float av = ASrc[col], dv = ADst[col];
        long rA = rowA + b * 4;
#pragma unroll
        for (int reg = 0; reg < 4; reg++) {
            out[(rA + reg) * FOUT + col] = f2fp8(cA[reg]);
            spA[reg] += cA[reg] * av;
            dpA[reg] += cA[reg] * dv;
        }
        if (doB) {
            long rB = rowB + b * 4;
#pragma unroll
            for (int reg = 0; reg < 4; reg++) {
                out[(rB + reg) * FOUT + col] = f2fp8(cB[reg]);
                spB[reg] += cB[reg] * av;
                dpB[reg] += cB[reg] * dv;
            }
        }
        if ((nt % NTH) == NTH - 1) {  // head boundary: reduce over 16 m-lanes
#pragma unroll
            for (int o = 1; o < 16; o <<= 1) {
#pragma unroll
                for (int reg = 0; reg < 4; reg++) {
                    spA[reg] += __shfl_xor(spA[reg], o, 64);
                    dpA[reg] += __shfl_xor(dpA[reg], o, 64);
                    spB[reg] += __shfl_xor(spB[reg], o, 64);
                    dpB[reg] += __shfl_xor(dpB[reg], o, 64);
                }
            }
            int hd = nt / NTH;
#pragma unroll
            for (int reg = 0; reg < 4; reg++) {
                if (m == hd) {
                    skA[reg] = spA[reg]; dkA[reg] = dpA[reg];
                    skB[reg] = spB[reg]; dkB[reg] = dpB[reg];
                }
                spA[reg] = 0.f; dpA[reg] = 0.f;
                spB[reg] = 0.f; dpB[reg] = 0.f;
            }
        }
    }
    if (m < HEADS) {
        long rA = rowA + b * 4;
#pragma unroll
        for (int reg = 0; reg < 4; reg++) {
            s_out_g[(rA + reg) * HEADS + m] = skA[reg];
            d_out_g[(rA + reg) * HEADS + m] = dkA[reg];
        }
        if (doB) {
            long rB = rowB + b * 4;
#pragma unroll
            for (int reg = 0; reg < 4; reg++) {
                s_out_g[(rB + reg) * HEADS + m] = skB[reg];
                d_out_g[(rB + reg) * HEADS + m] = dkB[reg];
            }
        }
    }
}

// ---- mega kernel: gemm1 FIRST (391 heavy blocks fill part of the machine)
// + edge count behind (3125 cheap atomic blocks fill the rest). Single
// stream -> this intra-kernel fusion is the ONLY concurrency available;
// splitting them (r8) serialized and regressed. Count records rank so the
// later scatter is atomic-free. ----
__global__ __launch_bounds__(256) void k_mega1(
        const float* __restrict__ x, const uint4* __restrict__ wpk,
        const float* __restrict__ asrc1, const float* __restrict__ adst1,
        unsigned char* __restrict__ u_h, float* __restrict__ f_s,
        float* __restrict__ f_d, const int* __restrict__ ei,
        int* __restrict__ counts, int* __restrict__ rank) {
    if (blockIdx.x < GEMM_GRID) {
        gemm_body<IN_CH, F1, false>(x, wpk, asrc1, adst1, u_h, f_s, f_d,
                                    N_NODES, blockIdx.x);
    } else {
        int e = (blockIdx.x - GEMM_GRID) * 256 + threadIdx.x;
        if (e < N_EDGES) {
            int dst = ei[N_EDGES + e];
            rank[e] = atomicAdd(&counts[dst], 1);
        }
    }
}

__global__ __launch_bounds__(256) void k_gemm2(
        const ushortT* __restrict__ A, const uint4* __restrict__ wpk2,
        const float* __restrict__ asrc2, const float* __restrict__ adst2,
        unsigned char* __restrict__ u_h, float* __restrict__ f_s,
        float* __restrict__ f_d) {
    gemm_body<F1, F2, true>(A, wpk2, asrc2, adst2, u_h, f_s, f_d,
                            N_NODES, blockIdx.x);
}

// ---- 2-phase exclusive scan (consumers add bbase inline) ----
__global__ void k_scan1(const int* __restrict__ counts, int* __restrict__ offs,
                        int* __restrict__ bsum) {
    __shared__ int sh[SCAN_B];
    int b = blockIdx.x, t = threadIdx.x;
    int i = b * SCAN_B + t;
    int v = (i < N_NODES) ? counts[i] : 0;
    sh[t] = v;
    __syncthreads();
    for (int o = 1; o < SCAN_B; o <<= 1) {
        int add = (t >= o) ? sh[t - o] : 0;
        __syncthreads();
        sh[t] += add;
        __syncthreads();
    }
    if (i < N_NODES) offs[i] = sh[t] - v;  // block-local exclusive
    if (t == SCAN_B - 1) bsum[b] = sh[t];
}

__global__ void k_scan2(const int* __restrict__ bsum, int* __restrict__ bbase,
                        int* __restrict__ offs, const int* __restrict__ batch,
                        int* __restrict__ bounds) {
    __shared__ int sh[SCAN_B];
    int t = threadIdx.x;
    int v = (t < SCAN_NB) ? bsum[t] : 0;
    sh[t] = v;
    __syncthreads();
    for (int o = 1; o < SCAN_B; o <<= 1) {
        int add = (t >= o) ? sh[t - o] : 0;
        __syncthreads();
        sh[t] += add;
        __syncthreads();
    }
    if (t < SCAN_NB) bbase[t] = sh[t] - v;      // exclusive base per block
    if (t == SCAN_B - 1) offs[N_NODES] = sh[t]; // grand total (= N_EDGES)
    // fused: graph boundaries via binary search on sorted batch
    if (t <= N_GRAPHS) {
        int lo = 0, hi = N_NODES;
        while (lo < hi) {
            int mid = (lo + hi) >> 1;
            if (batch[mid] < t) lo = mid + 1; else hi = mid;
        }
        bounds[t] = lo;
    }
}

// ---- scatter: ATOMIC-FREE (rank precomputed during count) ----
__global__ void k_scatter(const int* __restrict__ ei, const int* __restrict__ offs,
                          const int* __restrict__ bbase, const int* __restrict__ rank,
                          int* __restrict__ csr_src) {
    int e = blockIdx.x * blockDim.x + threadIdx.x;
    if (e >= N_EDGES) return;
    int src = ei[e], dst = ei[N_EDGES + e];
    int pos = offs[dst] + bbase[dst >> 8] + rank[e];
    csr_src[pos] = src;
}

// ---- fused segment-softmax + aggregation: TWO nodes per wave (32 lanes
// each), no barriers. Mean degree 16: 2 nodes/wave halves wave-instructions
// per edge (measured bottleneck: VALU issue). ----
template <int C, int VEC, int WPB, int CHUNK>
__global__ __launch_bounds__(64 * WPB) void k_agg(
        const unsigned char* __restrict__ hb, const float* __restrict__ s,
        const float* __restrict__ d, const int* __restrict__ offs,
        const int* __restrict__ bbase, const int* __restrict__ csr_src,
        const float* __restrict__ bias, ushortT* __restrict__ xout) {
    constexpr int F = HEADS * C;
    constexpr int TPN = F / VEC;  // lanes per node
    static_assert(TPN == 32, "two nodes per wave");
    static_assert(C / VEC == 8, "head = tl>>3");
    static_assert(N_NODES % (WPB * 2) == 0, "exact grid");
    __shared__ int lsrc[WPB][2][CHUNK];
    __shared__ float lex[WPB][2][CHUNK * HEADS];
    int wv = threadIdx.x >> 6;
    int t = threadIdx.x & 63;
    int half = t >> 5, tl = t & 31;
    int n = (blockIdx.x * WPB + wv) * 2 + half;
    int h = tl >> 3;
    int beg = offs[n] + bbase[n >> 8];
    int np1 = n + 1;
    int end = (np1 < N_NODES) ? offs[np1] + bbase[np1 >> 8] : offs[N_NODES];
    float4 dn = *(const float4*)(d + n * 4);

    // implicit self-loop: init sumex/acc from own s,d,h (outside the hot loop)
    float4 svn = *(const float4*)(s + n * 4);
    float ssel = (h == 0) ? svn.x : (h == 1) ? svn.y : (h == 2) ? svn.z : svn.w;
    float dsel = (h == 0) ? dn.x : (h == 1) ? dn.y : (h == 2) ? dn.z : dn.w;
    float es = ssel + dsel; es = es > 0.f ? es : 0.2f * es;
    float exs = __expf(es);
    float sumex = exs;
    float acc[VEC];
    if (VEC == 8) {
        uint2 w = ((const uint2*)hb)[(long)n * TPN + tl];
        v2f p0 = __builtin_amdgcn_cvt_pk_f32_fp8(w.x, false);
        v2f p1 = __builtin_amdgcn_cvt_pk_f32_fp8(w.x, true);
        v2f p2 = __builtin_amdgcn_cvt_pk_f32_fp8(w.y, false);
        v2f p3 = __builtin_amdgcn_cvt_pk_f32_fp8(w.y, true);
        acc[0] = exs * p0.x; acc[1] = exs * p0.y;
        acc[2] = exs * p1.x; acc[3] = exs * p1.y;
        acc[4] = exs * p2.x; acc[5] = exs * p2.y;
        acc[6] = exs * p3.x; acc[7] = exs * p3.y;
    } else {
        uintT w = ((const uintT*)hb)[(long)n * TPN + tl];
        v2f p0 = __builtin_amdgcn_cvt_pk_f32_fp8(w, false);
        v2f p1 = __builtin_amdgcn_cvt_pk_f32_fp8(w, true);
        acc[0] = exs * p0.x; acc[1] = exs * p0.y;
        acc[2] = exs * p1.x; acc[3] = exs * p1.y;
    }

    int tot = end - beg;                      // uniform within a half
    int totO = __shfl_xor(tot, 32, 64);       // other half's count
    int maxTot = max(tot, totO);
    for (int base = 0; base < maxTot; base += CHUNK) {
        int cnt = min(CHUNK, tot - base); if (cnt < 0) cnt = 0;
        int cntW = min(CHUNK, maxTot - base);  // wave-uniform loop bound
        // phase 1: each half stages its own node's edges (32 lanes active)
        for (int i = tl; i < cnt; i += TPN) {
            int sn = csr_src[beg + base + i];
            lsrc[wv][half][i] = sn;
            float4 sv = *(const float4*)(s + sn * 4);
            float e0 = sv.x + dn.x; e0 = e0 > 0.f ? e0 : 0.2f * e0;
            float e1 = sv.y + dn.y; e1 = e1 > 0.f ? e1 : 0.2f * e1;
            float e2 = sv.z + dn.z; e2 = e2 > 0.f ? e2 : 0.2f * e2;
            float e3 = sv.w + dn.w; e3 = e3 > 0.f ? e3 : 0.2f * e3;
            float4 exv = { __expf(e0), __expf(e1), __expf(e2), __expf(e3) };
            *(float4*)&lex[wv][half][i * 4] = exv;
        }
        // intra-wave LDS write->read ordering (no block barrier needed)
        asm volatile("s_waitcnt lgkmcnt(0)" ::: "memory");
        // phase 2: both halves accumulate in lockstep; shorter half padded
        // with ex=0 / sn=0 (branchless, finite data -> adds exact 0)
#pragma unroll 4
        for (int i = 0; i < cntW; i++) {
            bool act = i < cnt;
            float ex = act ? lex[wv][half][i * 4 + h] : 0.f;
            int sn = act ? lsrc[wv][half][i] : 0;
            sumex += ex;
            if (VEC == 8) {
                uint2 w = ((const uint2*)hb)[(long)sn * TPN + tl];
                v2f p0 = __builtin_amdgcn_cvt_pk_f32_fp8(w.x, false);
                v2f p1 = __builtin_amdgcn_cvt_pk_f32_fp8(w.x, true);
                v2f p2 = __builtin_amdgcn_cvt_pk_f32_fp8(w.y, false);
                v2f p3 = __builtin_amdgcn_cvt_pk_f32_fp8(w.y, true);
                acc[0] += ex * p0.x; acc[1] += ex * p0.y;
                acc[2] += ex * p1.x; acc[3] += ex * p1.y;
                acc[4] += ex * p2.x; acc[5] += ex * p2.y;
                acc[6] += ex * p3.x; acc[7] += ex * p3.y;
            } else {
                uintT w = ((const uintT*)hb)[(long)sn * TPN + tl];
                v2f p0 = __builtin_amdgcn_cvt_pk_f32_fp8(w, false);
                v2f p1 = __builtin_amdgcn_cvt_pk_f32_fp8(w, true);
                acc[0] += ex * p0.x; acc[1] += ex * p0.y;
                acc[2] += ex * p1.x; acc[3] += ex * p1.y;
            }
        }
        asm volatile("" ::: "memory");
    }
    float inv = 1.f / (sumex + 1e-16f);
    float o[VEC];
#pragma unroll
    for (int j = 0; j < VEC; j++)
        o[j] = fmaxf(acc[j] * inv + bias[tl * VEC + j], 0.f);
    if (VEC == 8) {
        uint4 pk;
        pk.x = (uintT)f2bf(o[0]) | ((uintT)f2bf(o[1]) << 16);
        pk.y = (uintT)f2bf(o[2]) | ((uintT)f2bf(o[3]) << 16);
        pk.z = (uintT)f2bf(o[4]) | ((uintT)f2bf(o[5]) << 16);
        pk.w = (uintT)f2bf(o[6]) | ((uintT)f2bf(o[7]) << 16);
        ((uint4*)xout)[(long)n * TPN + tl] = pk;
    } else {
        uint2 pk;
        pk.x = (uintT)f2bf(o[0]) | ((uintT)f2bf(o[1]) << 16);
        pk.y = (uintT)f2bf(o[2]) | ((uintT)f2bf(o[3]) << 16);
        ((uint2*)xout)[(long)n * TPN + tl] = pk;
    }
}

// ---- pool partials over bf16 x2: block (g,s) sums a contiguous slice ----
__global__ void k_pool_partial(const ushortT* __restrict__ x2, const int* __restrict__ bounds,
                               float* __restrict__ partial) {
    int g = blockIdx.x, s = blockIdx.y;
    int t = threadIdx.x;  // F2 threads
    int n0 = bounds[g], n1 = bounds[g + 1];
    int len = n1 - n0;
    int a = n0 + (int)((long)len * s / POOL_SPLITS);
    int b = n0 + (int)((long)len * (s + 1) / POOL_SPLITS);
    float acc = 0.f;
    for (int n = a; n < b; n++) acc += bf_lo((uintT)x2[(long)n * F2 + t]);
    partial[((long)g * POOL_SPLITS + s) * F2 + t] = acc;
}

// ---- head: block per graph — reduce partials, mean, logits, softmax ----
__global__ void k_head(const float* __restrict__ partial, const int* __restrict__ bounds,
                       const float* __restrict__ Wout, const float* __restrict__ bout,
                       float* __restrict__ out) {
    __shared__ float red0[F2], red1[F2];
    int g = blockIdx.x;
    int t = threadIdx.x;
    int cntN = bounds[g + 1] - bounds[g];
    float cnt = fmaxf((float)cntN, 1.0f);
    float sum = 0.f;
    for (int s = 0; s < POOL_SPLITS; s++)
        sum += partial[((long)g * POOL_SPLITS + s) * F2 + t];
    float p = sum / cnt;
    red0[t] = p * Wout[t * 2 + 0];
    red1[t] = p * Wout[t * 2 + 1];
    __syncthreads();
    for (int off = F2 / 2; off > 0; off >>= 1) {
        if (t < off) { red0[t] += red0[t + off]; red1[t] += red1[t + off]; }
        __syncthreads();
    }
    if (t == 0) {
        float l0 = red0[0] + bout[0];
        float l1 = red1[0] + bout[1];
        float m = fmaxf(l0, l1);
        float e0 = __expf(l0 - m), e1 = __expf(l1 - m);
        float inv = 1.f / (e0 + e1);
        out[g * 2 + 0] = e0 * inv;
        out[g * 2 + 1] = e1 * inv;
    }
}

extern "C" void kernel_launch(void* const* d_in, const int* in_sizes, int n_in,
                              void* d_out, int out_size, void* d_ws, size_t ws_size,
                              hipStream_t stream) {
    const float* x     = (const float*)d_in[0];
    const int*   ei    = (const int*)d_in[1];
    const int*   batch = (const int*)d_in[2];
    const float* W1    = (const float*)d_in[3];
    const float* asrc1 = (const float*)d_in[4];
    const float* adst1 = (const float*)d_in[5];
    const float* b1    = (const float*)d_in[6];
    const float* W2    = (const float*)d_in[7];
    const float* asrc2 = (const float*)d_in[8];
    const float* adst2 = (const float*)d_in[9];
    const float* b2    = (const float*)d_in[10];
    const float* Wout  = (const float*)d_in[11];
    const float* bout  = (const float*)d_in[12];

    char* ws = (char*)d_ws;
    size_t off = 0;
    auto alloc = [&](size_t bytes) -> void* {
        void* p = ws + off;
        off += (bytes + 255) / 256 * 256;
        return p;
    };
    unsigned char* u_h = (unsigned char*)alloc((size_t)N_NODES * F1);  // fp8 h (both layers)
    ushortT* u_x1  = (ushortT*)alloc(sizeof(ushortT) * (size_t)N_NODES * F1);
    ushortT* u_x2  = (ushortT*)alloc(sizeof(ushortT) * (size_t)N_NODES * F2);
    uint4*   wpk   = (uint4*)alloc(sizeof(uint4) * 8192);  // W1|W2 fragment images
    float*   f_s   = (float*)alloc(sizeof(float) * (size_t)N_NODES * HEADS);
    float*   f_d   = (float*)alloc(sizeof(float) * (size_t)N_NODES * HEADS);
    int*     i_cnt = (int*)alloc(sizeof(int) * (size_t)N_NODES);
    int*     i_off = (int*)alloc(sizeof(int) * (size_t)(N_NODES + 1));
    int*     i_rnk = (int*)alloc(sizeof(int) * (size_t)N_EDGES);
    int*     i_csr = (int*)alloc(sizeof(int) * (size_t)N_EDGES);
    int*     i_bnd = (int*)alloc(sizeof(int) * (size_t)(N_GRAPHS + 1));
    int*     i_bs  = (int*)alloc(sizeof(int) * SCAN_NB);
    int*     i_bb  = (int*)alloc(sizeof(int) * SCAN_NB);
    float*   f_prt = (float*)alloc(sizeof(float) * (size_t)N_GRAPHS * POOL_SPLITS * F2);
    (void)ws_size; (void)in_sizes; (void)n_in; (void)out_size;

    hipMemsetAsync(i_cnt, 0, sizeof(int) * N_NODES, stream);

    // tiny W-only pack (x consumed fp32 directly by gemm1)
    k_packw<<<32, 256, 0, stream>>>(W1, W2, wpk);

    // mega: gemm1 (fp32 A inline-cvt, no LDS, fp8 out) + CSR count-with-rank
    k_mega1<<<GEMM_GRID + COUNT_GRID, 256, 0, stream>>>(
        x, wpk, asrc1, adst1, u_h, f_s, f_d, ei, i_cnt, i_rnk);

    // 2-phase scan (+bounds); atomic-free scatter using precomputed ranks
    k_scan1<<<SCAN_NB, SCAN_B, 0, stream>>>(i_cnt, i_off, i_bs);
    k_scan2<<<1, SCAN_B, 0, stream>>>(i_bs, i_bb, i_off, batch, i_bnd);
    k_scatter<<<COUNT_GRID, 256, 0, stream>>>(ei, i_off, i_bb, i_rnk, i_csr);

    int agg_grid = N_NODES / (4 * 2);  // 2 nodes/wave, 4 waves/block = 6250

    // Layer 1 aggregation (fp8 gather, 2 nodes per wave, VEC=8)
    k_agg<HID, 8, 4, 128><<<agg_grid, 256, 0, stream>>>(
        u_h, f_s, f_d, i_off, i_bb, i_csr, b1, u_x1);

    // Layer 2
    k_gemm2<<<GEMM_GRID, 256, 0, stream>>>(u_x1, wpk + 4096, asrc2, adst2,
                                           u_h, f_s, f_d);
    k_agg<OUT_CH, 4, 4, 128><<<agg_grid, 256, 0, stream>>>(
        u_h, f_s, f_d, i_off, i_bb, i_csr, b2, u_x2);

    // Pool (1024 blocks, machine-filling) + tiny head
    dim3 pgrid(N_GRAPHS, POOL_SPLITS);
    k_pool_partial<<<pgrid, F2, 0, stream>>>(u_x2, i_bnd, f_prt);
    k_head<<<N_GRAPHS, F2, 0, stream>>>(f_prt, i_bnd, Wout, bout, (float*)d_out);
}

// Round 10
// 254.723 us; speedup vs baseline: 1.1291x; 1.0438x over previous
//
#include <hip/hip_runtime.h>
#include <hip/hip_bf16.h>

#define N_NODES 50000
#define N_EDGES 800000
#define N_GRAPHS 64
#define HEADS 4
#define IN_CH 128
#define HID 64
#define F1 256  // HEADS*HID
#define OUT_CH 32
#define F2 128  // HEADS*OUT_CH
#define POOL_SPLITS 16
#define SCAN_B 256
#define SCAN_NB ((N_NODES + SCAN_B - 1) / SCAN_B)  // 196
#define GEMM_GRID ((N_NODES + 63) / 64)            // 782 (64 rows/block, 1 tile/wave)
#define COUNT_GRID ((N_EDGES + 255) / 256)         // 3125

typedef unsigned short ushortT;
typedef unsigned int uintT;
typedef short v8s __attribute__((ext_vector_type(8)));
typedef float v4f __attribute__((ext_vector_type(4)));
typedef float v2f __attribute__((ext_vector_type(2)));

__device__ __forceinline__ ushortT f2bf(float f) {
    union { float f; unsigned int i; } v; v.f = f;
    unsigned int x = v.i;
    unsigned int r = (x + 0x7fffu + ((x >> 16) & 1u)) >> 16;  // RNE
    return (ushortT)r;
}
__device__ __forceinline__ float bf_lo(uintT w) {
    union { unsigned int i; float f; } v; v.i = w << 16; return v.f;
}
__device__ __forceinline__ float bf_hi(uintT w) {
    union { unsigned int i; float f; } v; v.i = w & 0xffff0000u; return v.f;
}
// fp8 e4m3 (OCP on gfx950) via HW converts
__device__ __forceinline__ unsigned char f2fp8(float f) {
    return (unsigned char)__builtin_amdgcn_cvt_pk_fp8_f32(f, f, 0u, false);
}

// ---- one-time weight pack into bf16 B-fragment image + fused i_cnt zeroing
// (saves the hipMemsetAsync dispatch; single stream = launches serialize) ----
__device__ __forceinline__ void packW_one(const float* __restrict__ W,
                                          uint4* __restrict__ dst,
                                          int i, int FIN, int FOUT) {
    int KC = FIN / 32;
    int lane = i & 63, g = i >> 6;
    int kc = g % KC, nt = g / KC;
    int n = nt * 16 + (lane & 15);
    int kbase = kc * 32 + (lane >> 4) * 8;
    union { uint4 q; ushortT u[8]; } pk;
#pragma unroll
    for (int j = 0; j < 8; j++) pk.u[j] = f2bf(W[(kbase + j) * FOUT + n]);
    dst[i] = pk.q;
}

__global__ __launch_bounds__(256) void k_packw(
        const float* __restrict__ W1, const float* __restrict__ W2,
        uint4* __restrict__ wpk, int* __restrict__ counts) {
    int i = blockIdx.x * 256 + threadIdx.x;  // 8192 = 4096 (W1) + 4096 (W2)
    if (i < 4096) packW_one(W1, wpk, i, IN_CH, F1);
    else          packW_one(W2, wpk + 4096, i - 4096, F1, F2);
    for (int j = i; j < N_NODES; j += 8192) counts[j] = 0;  // fused memset
}

// ---- MFMA GEMM, 64-row block, ONE 16-row tile per wave ----
// r9 showed the 128-row/391-block shape leaves the machine at 16% occupancy
// (1.5 blocks/CU after count blocks drain) — a latency-bound tail. 782
// blocks = 3 blocks/CU, each wave owns a distinct tile (no redundant A
// loads, unlike r4's failed 16-row variant). W image stays L2-resident.
template <int FIN, int FOUT, bool ABF16>
__device__ __forceinline__ void gemm_body(const void* __restrict__ A,
                                          const uint4* __restrict__ Wpk,
                                          const float* __restrict__ ASrc,
                                          const float* __restrict__ ADst,
                                          unsigned char* __restrict__ out,
                                          float* __restrict__ s_out_g,
                                          float* __restrict__ d_out_g,
                                          int nrows, int bid) {
    constexpr int KC = FIN / 32;
    constexpr int NT = FOUT / 16;
    constexpr int NTH = (FOUT / HEADS) / 16;  // nt tiles per head
    int tid = threadIdx.x;
    int wave = tid >> 6, lane = tid & 63;
    long row0 = (long)bid * 64 + wave * 16;
    if (row0 >= nrows) return;  // wave-uniform (nrows % 16 == 0)
    int m = lane & 15, b = lane >> 4;

    v8s af[KC];
    if (ABF16) {
        const ushortT* Ab = (const ushortT*)A;
#pragma unroll
        for (int kc = 0; kc < KC; kc++) {
            union { v8s v; uint4 q; } u;
            u.q = *(const uint4*)(Ab + (row0 + m) * FIN + kc * 32 + b * 8);
            af[kc] = u.v;
        }
    } else {
        const float* Af = (const float*)A;
#pragma unroll
        for (int kc = 0; kc < KC; kc++) {
            union { v8s v; ushortT u[8]; } u;
            const float* p = Af + (row0 + m) * FIN + kc * 32 + b * 8;
#pragma unroll
            for (int j = 0; j < 8; j++) u.u[j] = f2bf(p[j]);
            af[kc] = u.v;
        }
    }

    float sp[4] = {0,0,0,0}, dp[4] = {0,0,0,0};
    float sk[4], dk[4];
#pragma unroll
    for (int nt = 0; nt < NT; nt++) {
        v4f c = {0.f, 0.f, 0.f, 0.f};
#pragma unroll
        for (int kc = 0; kc < KC; kc++) {
            union { v8s v; uint4 q; } bu;
            bu.q = Wpk[(nt * KC + kc) * 64 + lane];
            c = __builtin_amdgcn_mfma_f32_16x16x32_bf16(af[kc], bu.v, c, 0, 0, 0);
        }
        // C/D: col = lane&15, row = (lane>>4)*4 + reg   [measured m89/m91]
        int col = nt * 16 + m;
        float av = ASrc[col], dv = ADst[col];
        long r0 = row0 + b * 4;
#pragma unroll
        for (int reg = 0; reg < 4; reg++) {
            out[(r0 + reg) * FOUT + col] = f2fp8(c[reg]);
            sp[reg] += c[reg] * av;
            dp[reg] += c[reg] * dv;
        }
        if ((nt % NTH) == NTH - 1) {  // head boundary: reduce over 16 m-lanes
#pragma unroll
            for (int o = 1; o < 16; o <<= 1) {
#pragma unroll
                for (int reg = 0; reg < 4; reg++) {
                    sp[reg] += __shfl_xor(sp[reg], o, 64);
                    dp[reg] += __shfl_xor(dp[reg], o, 64);
                }
            }
            int hd = nt / NTH;
#pragma unroll
            for (int reg = 0; reg < 4; reg++) {
                if (m == hd) { sk[reg] = sp[reg]; dk[reg] = dp[reg]; }
                sp[reg] = 0.f; dp[reg] = 0.f;
            }
        }
    }
    if (m < HEADS) {
        long r0 = row0 + b * 4;
#pragma unroll
        for (int reg = 0; reg < 4; reg++) {
            s_out_g[(r0 + reg) * HEADS + m] = sk[reg];
            d_out_g[(r0 + reg) * HEADS + m] = dk[reg];
        }
    }
}

// ---- mega kernel: gemm1 FIRST (782 blocks) + edge count behind (3125
// cheap atomic blocks). Single stream -> intra-kernel fusion is the only
// concurrency; count records rank so the later scatter is atomic-free. ----
__global__ __launch_bounds__(256) void k_mega1(
        const float* __restrict__ x, const uint4* __restrict__ wpk,
        const float* __restrict__ asrc1, const float* __restrict__ adst1,
        unsigned char* __restrict__ u_h, float* __restrict__ f_s,
        float* __restrict__ f_d, const int* __restrict__ ei,
        int* __restrict__ counts, int* __restrict__ rank) {
    if (blockIdx.x < GEMM_GRID) {
        gemm_body<IN_CH, F1, false>(x, wpk, asrc1, adst1, u_h, f_s, f_d,
                                    N_NODES, blockIdx.x);
    } else {
        int e = (blockIdx.x - GEMM_GRID) * 256 + threadIdx.x;
        if (e < N_EDGES) {
            int dst = ei[N_EDGES + e];
            rank[e] = atomicAdd(&counts[dst], 1);
        }
    }
}

__global__ __launch_bounds__(256) void k_gemm2(
        const ushortT* __restrict__ A, const uint4* __restrict__ wpk2,
        const float* __restrict__ asrc2, const float* __restrict__ adst2,
        unsigned char* __restrict__ u_h, float* __restrict__ f_s,
        float* __restrict__ f_d) {
    gemm_body<F1, F2, true>(A, wpk2, asrc2, adst2, u_h, f_s, f_d,
                            N_NODES, blockIdx.x);
}

// ---- 2-phase exclusive scan (consumers add bbase inline) ----
__global__ void k_scan1(const int* __restrict__ counts, int* __restrict__ offs,
                        int* __restrict__ bsum) {
    __shared__ int sh[SCAN_B];
    int b = blockIdx.x, t = threadIdx.x;
    int i = b * SCAN_B + t;
    int v = (i < N_NODES) ? counts[i] : 0;
    sh[t] = v;
    __syncthreads();
    for (int o = 1; o < SCAN_B; o <<= 1) {
        int add = (t >= o) ? sh[t - o] : 0;
        __syncthreads();
        sh[t] += add;
        __syncthreads();
    }
    if (i < N_NODES) offs[i] = sh[t] - v;  // block-local exclusive
    if (t == SCAN_B - 1) bsum[b] = sh[t];
}

__global__ void k_scan2(const int* __restrict__ bsum, int* __restrict__ bbase,
                        int* __restrict__ offs, const int* __restrict__ batch,
                        int* __restrict__ bounds) {
    __shared__ int sh[SCAN_B];
    int t = threadIdx.x;
    int v = (t < SCAN_NB) ? bsum[t] : 0;
    sh[t] = v;
    __syncthreads();
    for (int o = 1; o < SCAN_B; o <<= 1) {
        int add = (t >= o) ? sh[t - o] : 0;
        __syncthreads();
        sh[t] += add;
        __syncthreads();
    }
    if (t < SCAN_NB) bbase[t] = sh[t] - v;      // exclusive base per block
    if (t == SCAN_B - 1) offs[N_NODES] = sh[t]; // grand total (= N_EDGES)
    // fused: graph boundaries via binary search on sorted batch
    if (t <= N_GRAPHS) {
        int lo = 0, hi = N_NODES;
        while (lo < hi) {
            int mid = (lo + hi) >> 1;
            if (batch[mid] < t) lo = mid + 1; else hi = mid;
        }
        bounds[t] = lo;
    }
}

// ---- scatter: ATOMIC-FREE (rank precomputed during count) ----
__global__ void k_scatter(const int* __restrict__ ei, const int* __restrict__ offs,
                          const int* __restrict__ bbase, const int* __restrict__ rank,
                          int* __restrict__ csr_src) {
    int e = blockIdx.x * blockDim.x + threadIdx.x;
    if (e >= N_EDGES) return;
    int src = ei[e], dst = ei[N_EDGES + e];
    int pos = offs[dst] + bbase[dst >> 8] + rank[e];
    csr_src[pos] = src;
}

// ---- fused segment-softmax + aggregation: TWO nodes per wave (32 lanes
// each), no barriers. Mean degree 16: 2 nodes/wave halves wave-instructions
// per edge (measured bottleneck: VALU issue). ----
template <int C, int VEC, int WPB, int CHUNK>
__global__ __launch_bounds__(64 * WPB) void k_agg(
        const unsigned char* __restrict__ hb, const float* __restrict__ s,
        const float* __restrict__ d, const int* __restrict__ offs,
        const int* __restrict__ bbase, const int* __restrict__ csr_src,
        const float* __restrict__ bias, ushortT* __restrict__ xout) {
    constexpr int F = HEADS * C;
    constexpr int TPN = F / VEC;  // lanes per node
    static_assert(TPN == 32, "two nodes per wave");
    static_assert(C / VEC == 8, "head = tl>>3");
    static_assert(N_NODES % (WPB * 2) == 0, "exact grid");
    __shared__ int lsrc[WPB][2][CHUNK];
    __shared__ float lex[WPB][2][CHUNK * HEADS];
    int wv = threadIdx.x >> 6;
    int t = threadIdx.x & 63;
    int half = t >> 5, tl = t & 31;
    int n = (blockIdx.x * WPB + wv) * 2 + half;
    int h = tl >> 3;
    int beg = offs[n] + bbase[n >> 8];
    int np1 = n + 1;
    int end = (np1 < N_NODES) ? offs[np1] + bbase[np1 >> 8] : offs[N_NODES];
    float4 dn = *(const float4*)(d + n * 4);

    // implicit self-loop: init sumex/acc from own s,d,h (outside the hot loop)
    float4 svn = *(const float4*)(s + n * 4);
    float ssel = (h == 0) ? svn.x : (h == 1) ? svn.y : (h == 2) ? svn.z : svn.w;
    float dsel = (h == 0) ? dn.x : (h == 1) ? dn.y : (h == 2) ? dn.z : dn.w;
    float es = ssel + dsel; es = es > 0.f ? es : 0.2f * es;
    float exs = __expf(es);
    float sumex = exs;
    float acc[VEC];
    if (VEC == 8) {
        uint2 w = ((const uint2*)hb)[(long)n * TPN + tl];
        v2f p0 = __builtin_amdgcn_cvt_pk_f32_fp8(w.x, false);
        v2f p1 = __builtin_amdgcn_cvt_pk_f32_fp8(w.x, true);
        v2f p2 = __builtin_amdgcn_cvt_pk_f32_fp8(w.y, false);
        v2f p3 = __builtin_amdgcn_cvt_pk_f32_fp8(w.y, true);
        acc[0] = exs * p0.x; acc[1] = exs * p0.y;
        acc[2] = exs * p1.x; acc[3] = exs * p1.y;
        acc[4] = exs * p2.x; acc[5] = exs * p2.y;
        acc[6] = exs * p3.x; acc[7] = exs * p3.y;
    } else {
        uintT w = ((const uintT*)hb)[(long)n * TPN + tl];
        v2f p0 = __builtin_amdgcn_cvt_pk_f32_fp8(w, false);
        v2f p1 = __builtin_amdgcn_cvt_pk_f32_fp8(w, true);
        acc[0] = exs * p0.x; acc[1] = exs * p0.y;
        acc[2] = exs * p1.x; acc[3] = exs * p1.y;
    }

    int tot = end - beg;                      // uniform within a half
    int totO = __shfl_xor(tot, 32, 64);       // other half's count
    int maxTot = max(tot, totO);
    for (int base = 0; base < maxTot; base += CHUNK) {
        int cnt = min(CHUNK, tot - base); if (cnt < 0) cnt = 0;
        int cntW = min(CHUNK, maxTot - base);  // wave-uniform loop bound
        // phase 1: each half stages its own node's edges (32 lanes active)
        for (int i = tl; i < cnt; i += TPN) {
            int sn = csr_src[beg + base + i];
            lsrc[wv][half][i] = sn;
            float4 sv = *(const float4*)(s + sn * 4);
            float e0 = sv.x + dn.x; e0 = e0 > 0.f ? e0 : 0.2f * e0;
            float e1 = sv.y + dn.y; e1 = e1 > 0.f ? e1 : 0.2f * e1;
            float e2 = sv.z + dn.z; e2 = e2 > 0.f ? e2 : 0.2f * e2;
            float e3 = sv.w + dn.w; e3 = e3 > 0.f ? e3 : 0.2f * e3;
            float4 exv = { __expf(e0), __expf(e1), __expf(e2), __expf(e3) };
            *(float4*)&lex[wv][half][i * 4] = exv;
        }
        // intra-wave LDS write->read ordering (no block barrier needed)
        asm volatile("s_waitcnt lgkmcnt(0)" ::: "memory");
        // phase 2: both halves accumulate in lockstep; shorter half padded
        // with ex=0 / sn=0 (branchless, finite data -> adds exact 0)
#pragma unroll 4
        for (int i = 0; i < cntW; i++) {
            bool act = i < cnt;
            float ex = act ? lex[wv][half][i * 4 + h] : 0.f;
            int sn = act ? lsrc[wv][half][i] : 0;
            sumex += ex;
            if (VEC == 8) {
                uint2 w = ((const uint2*)hb)[(long)sn * TPN + tl];
                v2f p0 = __builtin_amdgcn_cvt_pk_f32_fp8(w.x, false);
                v2f p1 = __builtin_amdgcn_cvt_pk_f32_fp8(w.x, true);
                v2f p2 = __builtin_amdgcn_cvt_pk_f32_fp8(w.y, false);
                v2f p3 = __builtin_amdgcn_cvt_pk_f32_fp8(w.y, true);
                acc[0] += ex * p0.x; acc[1] += ex * p0.y;
                acc[2] += ex * p1.x; acc[3] += ex * p1.y;
                acc[4] += ex * p2.x; acc[5] += ex * p2.y;
                acc[6] += ex * p3.x; acc[7] += ex * p3.y;
            } else {
                uintT w = ((const uintT*)hb)[(long)sn * TPN + tl];
                v2f p0 = __builtin_amdgcn_cvt_pk_f32_fp8(w, false);
                v2f p1 = __builtin_amdgcn_cvt_pk_f32_fp8(w, true);
                acc[0] += ex * p0.x; acc[1] += ex * p0.y;
                acc[2] += ex * p1.x; acc[3] += ex * p1.y;
            }
        }
        asm volatile("" ::: "memory");
    }
    float inv = 1.f / (sumex + 1e-16f);
    float o[VEC];
#pragma unroll
    for (int j = 0; j < VEC; j++)
        o[j] = fmaxf(acc[j] * inv + bias[tl * VEC + j], 0.f);
    if (VEC == 8) {
        uint4 pk;
        pk.x = (uintT)f2bf(o[0]) | ((uintT)f2bf(o[1]) << 16);
        pk.y = (uintT)f2bf(o[2]) | ((uintT)f2bf(o[3]) << 16);
        pk.z = (uintT)f2bf(o[4]) | ((uintT)f2bf(o[5]) << 16);
        pk.w = (uintT)f2bf(o[6]) | ((uintT)f2bf(o[7]) << 16);
        ((uint4*)xout)[(long)n * TPN + tl] = pk;
    } else {
        uint2 pk;
        pk.x = (uintT)f2bf(o[0]) | ((uintT)f2bf(o[1]) << 16);
        pk.y = (uintT)f2bf(o[2]) | ((uintT)f2bf(o[3]) << 16);
        ((uint2*)xout)[(long)n * TPN + tl] = pk;
    }
}

// ---- pool partials over bf16 x2: block (g,s) sums a contiguous slice ----
__global__ void k_pool_partial(const ushortT* __restrict__ x2, const int* __restrict__ bounds,
                               float* __restrict__ partial) {
    int g = blockIdx.x, s = blockIdx.y;
    int t = threadIdx.x;  // F2 threads
    int n0 = bounds[g], n1 = bounds[g + 1];
    int len = n1 - n0;
    int a = n0 + (int)((long)len * s / POOL_SPLITS);
    int b = n0 + (int)((long)len * (s + 1) / POOL_SPLITS);
    float acc = 0.f;
    for (int n = a; n < b; n++) acc += bf_lo((uintT)x2[(long)n * F2 + t]);
    partial[((long)g * POOL_SPLITS + s) * F2 + t] = acc;
}

// ---- head: block per graph — reduce partials, mean, logits, softmax ----
__global__ void k_head(const float* __restrict__ partial, const int* __restrict__ bounds,
                       const float* __restrict__ Wout, const float* __restrict__ bout,
                       float* __restrict__ out) {
    __shared__ float red0[F2], red1[F2];
    int g = blockIdx.x;
    int t = threadIdx.x;
    int cntN = bounds[g + 1] - bounds[g];
    float cnt = fmaxf((float)cntN, 1.0f);
    float sum = 0.f;
    for (int s = 0; s < POOL_SPLITS; s++)
        sum += partial[((long)g * POOL_SPLITS + s) * F2 + t];
    float p = sum / cnt;
    red0[t] = p * Wout[t * 2 + 0];
    red1[t] = p * Wout[t * 2 + 1];
    __syncthreads();
    for (int off = F2 / 2; off > 0; off >>= 1) {
        if (t < off) { red0[t] += red0[t + off]; red1[t] += red1[t + off]; }
        __syncthreads();
    }
    if (t == 0) {
        float l0 = red0[0] + bout[0];
        float l1 = red1[0] + bout[1];
        float m = fmaxf(l0, l1);
        float e0 = __expf(l0 - m), e1 = __expf(l1 - m);
        float inv = 1.f / (e0 + e1);
        out[g * 2 + 0] = e0 * inv;
        out[g * 2 + 1] = e1 * inv;
    }
}

extern "C" void kernel_launch(void* const* d_in, const int* in_sizes, int n_in,
                              void* d_out, int out_size, void* d_ws, size_t ws_size,
                              hipStream_t stream) {
    const float* x     = (const float*)d_in[0];
    const int*   ei    = (const int*)d_in[1];
    const int*   batch = (const int*)d_in[2];
    const float* W1    = (const float*)d_in[3];
    const float* asrc1 = (const float*)d_in[4];
    const float* adst1 = (const float*)d_in[5];
    const float* b1    = (const float*)d_in[6];
    const float* W2    = (const float*)d_in[7];
    const float* asrc2 = (const float*)d_in[8];
    const float* adst2 = (const float*)d_in[9];
    const float* b2    = (const float*)d_in[10];
    const float* Wout  = (const float*)d_in[11];
    const float* bout  = (const float*)d_in[12];

    char* ws = (char*)d_ws;
    size_t off = 0;
    auto alloc = [&](size_t bytes) -> void* {
        void* p = ws + off;
        off += (bytes + 255) / 256 * 256;
        return p;
    };
    unsigned char* u_h = (unsigned char*)alloc((size_t)N_NODES * F1);  // fp8 h (both layers)
    ushortT* u_x1  = (ushortT*)alloc(sizeof(ushortT) * (size_t)N_NODES * F1);
    ushortT* u_x2  = (ushortT*)alloc(sizeof(ushortT) * (size_t)N_NODES * F2);
    uint4*   wpk   = (uint4*)alloc(sizeof(uint4) * 8192);  // W1|W2 fragment images
    float*   f_s   = (float*)alloc(sizeof(float) * (size_t)N_NODES * HEADS);
    float*   f_d   = (float*)alloc(sizeof(float) * (size_t)N_NODES * HEADS);
    int*     i_cnt = (int*)alloc(sizeof(int) * (size_t)N_NODES);
    int*     i_off = (int*)alloc(sizeof(int) * (size_t)(N_NODES + 1));
    int*     i_rnk = (int*)alloc(sizeof(int) * (size_t)N_EDGES);
    int*     i_csr = (int*)alloc(sizeof(int) * (size_t)N_EDGES);
    int*     i_bnd = (int*)alloc(sizeof(int) * (size_t)(N_GRAPHS + 1));
    int*     i_bs  = (int*)alloc(sizeof(int) * SCAN_NB);
    int*     i_bb  = (int*)alloc(sizeof(int) * SCAN_NB);
    float*   f_prt = (float*)alloc(sizeof(float) * (size_t)N_GRAPHS * POOL_SPLITS * F2);
    (void)ws_size; (void)in_sizes; (void)n_in; (void)out_size;

    // tiny W-only pack + fused i_cnt zeroing (memset launch deleted)
    k_packw<<<32, 256, 0, stream>>>(W1, W2, wpk, i_cnt);

    // mega: gemm1 (782 blocks, 1 tile/wave) + CSR count-with-rank behind
    k_mega1<<<GEMM_GRID + COUNT_GRID, 256, 0, stream>>>(
        x, wpk, asrc1, adst1, u_h, f_s, f_d, ei, i_cnt, i_rnk);

    // 2-phase scan (+bounds); atomic-free scatter using precomputed ranks
    k_scan1<<<SCAN_NB, SCAN_B, 0, stream>>>(i_cnt, i_off, i_bs);
    k_scan2<<<1, SCAN_B, 0, stream>>>(i_bs, i_bb, i_off, batch, i_bnd);
    k_scatter<<<COUNT_GRID, 256, 0, stream>>>(ei, i_off, i_bb, i_rnk, i_csr);

    int agg_grid = N_NODES / (4 * 2);  // 2 nodes/wave, 4 waves/block = 6250

    // Layer 1 aggregation (fp8 gather, 2 nodes per wave, VEC=8)
    k_agg<HID, 8, 4, 128><<<agg_grid, 256, 0, stream>>>(
        u_h, f_s, f_d, i_off, i_bb, i_csr, b1, u_x1);

    // Layer 2
    k_gemm2<<<GEMM_GRID, 256, 0, stream>>>(u_x1, wpk + 4096, asrc2, adst2,
                                           u_h, f_s, f_d);
    k_agg<OUT_CH, 4, 4, 128><<<agg_grid, 256, 0, stream>>>(
        u_h, f_s, f_d, i_off, i_bb, i_csr, b2, u_x2);

    // Pool (1024 blocks, machine-filling) + tiny head
    dim3 pgrid(N_GRAPHS, POOL_SPLITS);
    k_pool_partial<<<pgrid, F2, 0, stream>>>(u_x2, i_bnd, f_prt);
    k_head<<<N_GRAPHS, F2, 0, stream>>>(f_prt, i_bnd, Wout, bout, (float*)d_out);
}